// Round 13
// baseline (1387.899 us; speedup 1.0000x reference)
//
#include <hip/hip_runtime.h>
#include <math.h>

// Persistent-kernel ResonatorABC scan — tagged dataflow + linear-bin exact select.
// ROUND-13: 64 WGs x 512 threads (8 waves) — HALVED rendezvous participant count.
// WG w owns features [16w,16w+16) for ALL 128 rows; thread owns 4 (b,f):
// b = rg+32k (rg=tid>>4), f = 16w + (tid&15). WG w selects rows 2w and 2w+1 IN
// PARALLEL: waves 0-3 (tid<256) select row 2w, waves 4-7 select row 2w+1, on
// separate LDS buffers. Refine fallback = fixed-31-iteration bitwise radix
// select (uniform whole-WG control flow; data-independent termination).

#define T_STEPS 128
#define B_DIM   128
#define F_DIM   1024
#define NWG     64
#define NTH     512
#define BF      (B_DIM * F_DIM)

typedef unsigned long long ull;

__device__ __forceinline__ ull ld64(const ull* p) {
  return __hip_atomic_load(p, __ATOMIC_RELAXED, __HIP_MEMORY_SCOPE_AGENT);
}
__device__ __forceinline__ void st64(ull* p, ull v) {
  __hip_atomic_store(p, v, __ATOMIC_RELAXED, __HIP_MEMORY_SCOPE_AGENT);
}

extern "C" __global__ void __launch_bounds__(NTH)
ResonatorABC_82094004896068_kernel(
    const float* __restrict__ in_re, const float* __restrict__ in_im,
    const float* __restrict__ r_re_p, const float* __restrict__ r_im_p,
    const float* __restrict__ alpha_map, const float* __restrict__ lambda_map,
    float* __restrict__ out, ull* __restrict__ ws)
{
  const int tid  = threadIdx.x;
  const int wg   = blockIdx.x;
  const int fl   = tid & 15;         // feature-local index (0..15)
  const int rg   = tid >> 4;         // row-group base (0..31); rows rg+32k
  const int f    = (wg << 4) + fl;   // global feature
  const int wid  = tid >> 6;         // wave id (0..7)
  const int lane = tid & 63;
  const int half = tid >> 8;         // select-half (0/1)
  const int t2   = tid & 255;        // index within half
  const int wid2 = t2 >> 6;          // wave id within half (0..3)

  ull* score64 = ws;                 // [B][F] {tag|score_bits}
  ull* tauB64  = ws + BF;            // [128]
  ull* tauC64  = ws + BF + 128;      // [128]

  __shared__ __align__(16) float pamp[8][16][4];    // wave partials
  __shared__ __align__(16) float pfin[16][4];       // per-feature sums
  __shared__ __align__(16) float pev[8][16][2];     // wave ev partials
  __shared__ __align__(16) float evfin[16][2];      // per-feature ev sums
  __shared__ __align__(16) unsigned h2[2][1024];    // histograms (per half)
  __shared__ unsigned wsum2[2][4];                  // per-half wave scan totals
  __shared__ unsigned mmh[2][4][2];                 // per-half per-wave min/max
  __shared__ unsigned tbin2[2][4], tbase2[2][4], tcnt2[2][4];
  __shared__ unsigned lcnt2[2][4];
  __shared__ unsigned lists2[2][4][256];
  __shared__ unsigned resv2[2][4], resf2[2][4];
  __shared__ unsigned wred[8];                      // refine bit-count reduce
  __shared__ float tauLds[256];

  const float af = fminf(fmaxf(0.97f + 0.05f * tanhf(alpha_map[f]), 0.90f), 0.995f);
  const float lf = fminf(fmaxf(0.95f + 0.05f * tanhf(lambda_map[f]), 0.90f), 0.995f);
  const float rr = r_re_p[f];
  const float ri = r_im_p[f];
  const float c002 = cosf(0.02f);
  const float s002 = sinf(0.02f);

  float X_re[4] = {0.f,0.f,0.f,0.f}, X_im[4] = {0.f,0.f,0.f,0.f};
  float sA[4] = {0.f,0.f,0.f,0.f}, sB[4] = {0.f,0.f,0.f,0.f}, sC[4] = {0.f,0.f,0.f,0.f};
  float mu = 0.f, var = 0.01f, theta = 0.1f, ema_re = 0.f, ema_im = 0.f;

  int idx[4];
  float ur[4], ui[4];
  #pragma unroll
  for (int k = 0; k < 4; ++k) {
    idx[k] = (rg + 32 * k) * F_DIM + f;
    ur[k] = in_re[idx[k]];
    ui[k] = in_im[idx[k]];
  }

  const unsigned KR[4] = {255u, 256u, 767u, 768u};
  const int srow = 2 * wg + half;    // row this half selects

  for (int t = 0; t < T_STEPS; ++t) {
    const ull want = (ull)(t + 1);

    *(uint4*)&(((unsigned*)h2)[4 * tid]) = make_uint4(0u, 0u, 0u, 0u);  // 2048 words

    // ---------------- Phase 1: elementwise + B-reduced stats + score ----------------
    float Xm_re[4], Xm_im[4], proj[4], amp[4], score[4];
    float a0 = 0.f, a1 = 0.f, a2 = 0.f, a3 = 0.f;
    #pragma unroll
    for (int k = 0; k < 4; ++k) {
      Xm_re[k] = af * X_re[k] + ur[k];
      Xm_im[k] = af * X_im[k] + ui[k];
      float amp2 = Xm_re[k] * Xm_re[k] + Xm_im[k] * Xm_im[k];
      amp[k] = sqrtf(amp2);
      float invamp = (amp[k] > 0.f) ? (1.0f / amp[k]) : 0.f;
      float un_re = (amp[k] > 0.f) ? (Xm_re[k] * invamp) : 1.0f;  // angle(0)=0 -> unit=1
      float un_im = Xm_im[k] * invamp;
      proj[k] = Xm_re[k] * rr + Xm_im[k] * ri;                    // Re(X_mid*conj(r))
      sA[k] = lf * sA[k] + proj[k];
      out[t * BF + idx[k]] = sA[k];
      a0 += amp[k]; a1 += amp2; a2 += un_re; a3 += un_im;
    }
    #pragma unroll
    for (int m = 16; m < 64; m <<= 1) {   // reduce over the 4 row-groups in this wave
      a0 += __shfl_xor(a0, m);
      a1 += __shfl_xor(a1, m);
      a2 += __shfl_xor(a2, m);
      a3 += __shfl_xor(a3, m);
    }
    if (lane < 16) { *(float4*)&pamp[wid][lane][0] = make_float4(a0, a1, a2, a3); }
    __syncthreads();                                   // B1
    if (tid < 64) {   // summers: one per (feature, quantity)
      int sfl = tid >> 2, q = tid & 3;
      float s = 0.f;
      #pragma unroll
      for (int w = 0; w < 8; ++w) s += pamp[w][sfl][q];
      pfin[sfl][q] = s;
    }
    __syncthreads();                                   // B2
    float4 SS = *(const float4*)&pfin[fl][0];
    float m1 = SS.x * 0.0078125f;      // mean(amp)
    float m2 = SS.y * 0.0078125f;      // mean(amp^2)
    mu = 0.9f * mu + 0.1f * m1;
    float vm = m2 - 2.f * mu * m1 + mu * mu;
    vm = fmaxf(vm, 0.f);
    var = 0.9f * var + 0.1f * vm;
    ema_re = 0.9f * ema_re + 0.1f * (SS.z * 0.0078125f);
    ema_im = 0.9f * ema_im + 0.1f * (SS.w * 0.0078125f);
    float plv = sqrtf(ema_re * ema_re + ema_im * ema_im);
    float sden = sqrtf(var) + 1e-3f;
    #pragma unroll
    for (int k = 0; k < 4; ++k) {
      float zs = (amp[k] - mu) / sden;
      score[k] = amp[k] + 0.5f * fabsf(zs) + 0.5f * (1.0f - plv);
      st64(&score64[idx[k]], (want << 32) | (ull)__float_as_uint(score[k]));
    }

    // prefetch next-step inputs; latency hidden behind select
    float ur_n[4] = {0.f,0.f,0.f,0.f}, ui_n[4] = {0.f,0.f,0.f,0.f};
    if (t + 1 < T_STEPS) {
      #pragma unroll
      for (int k = 0; k < 4; ++k) {
        ur_n[k] = in_re[(t + 1) * BF + idx[k]];
        ui_n[k] = in_im[(t + 1) * BF + idx[k]];
      }
    }

    // ---------------- Phase 2: each half selects its row (parallel halves) ----------
    unsigned uval[4], bin[4];
    {
      const ull* sp0 = &score64[srow * F_DIM + t2];
      ull v[4]; bool ok[4] = {false, false, false, false};
      int remaining = 4;
      while (remaining) {
        #pragma unroll
        for (int k = 0; k < 4; ++k) if (!ok[k]) v[k] = ld64(sp0 + 256 * k);
        #pragma unroll
        for (int k = 0; k < 4; ++k) {
          if (!ok[k] && (v[k] >> 32) == want) { ok[k] = true; uval[k] = (unsigned)v[k]; --remaining; }
        }
        if (remaining) __builtin_amdgcn_s_sleep(1);
      }
    }
    unsigned umin = min(min(uval[0], uval[1]), min(uval[2], uval[3]));
    unsigned umax = max(max(uval[0], uval[1]), max(uval[2], uval[3]));
    #pragma unroll
    for (int m = 1; m < 64; m <<= 1) {
      umin = min(umin, (unsigned)__shfl_xor((int)umin, m));
      umax = max(umax, (unsigned)__shfl_xor((int)umax, m));
    }
    if (lane == 0) { mmh[half][wid2][0] = umin; mmh[half][wid2][1] = umax; }
    if (tid < 8) { lcnt2[tid >> 2][tid & 3] = 0u; resf2[tid >> 2][tid & 3] = 0u; }
    __syncthreads();                                   // B3
    unsigned lo = min(min(mmh[half][0][0], mmh[half][1][0]), min(mmh[half][2][0], mmh[half][3][0]));
    unsigned hi = max(max(mmh[half][0][1], mmh[half][1][1]), max(mmh[half][2][1], mmh[half][3][1]));

    // histogram (lo==hi degenerates to all-bin-0 -> refine resolves it; no divergence)
    ull rng = (ull)hi - (ull)lo + 1ull;
    ull inv = (rng > 1ull) ? ((1ull << 40) / rng) : (1ull << 40);
    #pragma unroll
    for (int k = 0; k < 4; ++k) {
      bin[k] = (unsigned)((((ull)(uval[k] - lo)) * inv) >> 30);
      atomicAdd(&h2[half][bin[k]], 1u);
    }
    __syncthreads();                                   // B4
    // scan within half: thread owns 4 consecutive bins
    uint4 hc = *(const uint4*)&h2[half][4 * t2];
    unsigned s4 = hc.x + hc.y + hc.z + hc.w;
    unsigned incl = s4;
    #pragma unroll
    for (int d = 1; d < 64; d <<= 1) {
      unsigned vv = __shfl_up(incl, d);
      if (lane >= d) incl += vv;
    }
    if (lane == 63) wsum2[half][wid2] = incl;
    __syncthreads();                                   // B5
    unsigned woff = 0u;
    for (int w = 0; w < 4; ++w) if (w < wid2) woff += wsum2[half][w];
    unsigned gexcl = woff + incl - s4;
    unsigned cv[4] = {hc.x, hc.y, hc.z, hc.w};
    unsigned bb[4];
    bb[0] = gexcl; bb[1] = bb[0] + cv[0]; bb[2] = bb[1] + cv[1]; bb[3] = bb[2] + cv[2];
    #pragma unroll
    for (int i = 0; i < 4; ++i) {
      if (cv[i] > 0u) {
        #pragma unroll
        for (int r = 0; r < 4; ++r) {
          if (bb[i] <= KR[r] && KR[r] < bb[i] + cv[i]) {
            tbin2[half][r] = 4 * t2 + i; tbase2[half][r] = bb[i]; tcnt2[half][r] = cv[i];
          }
        }
      }
    }
    __syncthreads();                                   // B6
    // build candidate lists (dedup: first list of each distinct bin; tbin non-decreasing)
    {
      unsigned b0 = tbin2[half][0], b1 = tbin2[half][1], b2 = tbin2[half][2], b3 = tbin2[half][3];
      #pragma unroll
      for (int k = 0; k < 4; ++k) {
        unsigned bk = bin[k], uv = uval[k];
        if (bk == b0) { unsigned s = atomicAdd(&lcnt2[half][0], 1u); if (s < 256u) lists2[half][0][s] = uv; }
        else if (bk == b1 && b1 != b0) { unsigned s = atomicAdd(&lcnt2[half][1], 1u); if (s < 256u) lists2[half][1][s] = uv; }
        else if (bk == b2 && b2 != b1) { unsigned s = atomicAdd(&lcnt2[half][2], 1u); if (s < 256u) lists2[half][2][s] = uv; }
        else if (bk == b3 && b3 != b2) { unsigned s = atomicAdd(&lcnt2[half][3], 1u); if (s < 256u) lists2[half][3][s] = uv; }
      }
    }
    __syncthreads();                                   // B7
    {   // wave (half, j=wid2) resolves rank j of its half — all 8 waves busy
      const int hh = half, j = wid2;
      int src = j;
      while (src > 0 && tbin2[hh][src - 1] == tbin2[hh][j]) --src;
      unsigned c = tcnt2[hh][j];
      if (c <= 256u) {
        unsigned kk = KR[j] - tbase2[hh][j];
        for (int bi = 0; bi < (int)c; bi += 64) {
          int i = bi + lane;
          if (i < (int)c) {
            unsigned e = lists2[hh][src][i];
            unsigned r = 0;
            for (int q = 0; q < (int)c; ++q) {
              unsigned x = lists2[hh][src][q];
              r += (x < e || (x == e && q < i)) ? 1u : 0u;
            }
            if (r == kk) { resv2[hh][j] = e; resf2[hh][j] = 1u; }
          }
        }
      }
    }
    __syncthreads();                                   // B8

    // rare exact refine: fixed-31-round bitwise radix select (uniform whole-WG flow)
    for (int hh = 0; hh < 2; ++hh) {
      for (int j = 0; j < 4; ++j) {
        if (resf2[hh][j]) continue;                    // uniform (LDS, post-sync)
        bool cand[4];
        #pragma unroll
        for (int k = 0; k < 4; ++k) cand[k] = (half == hh) && (bin[k] == tbin2[hh][j]);
        unsigned krem = KR[j] - tbase2[hh][j];
        unsigned val = 0u;
        for (int bit = 30; bit >= 0; --bit) {
          unsigned c0 = 0u;
          #pragma unroll
          for (int k = 0; k < 4; ++k)
            if (cand[k] && (((uval[k] >> bit) & 1u) == 0u)) ++c0;
          #pragma unroll
          for (int d = 1; d < 64; d <<= 1) c0 += (unsigned)__shfl_xor((int)c0, d);
          if (lane == 0) wred[wid] = c0;
          __syncthreads();
          unsigned cnt0 = 0u;
          #pragma unroll
          for (int w = 0; w < 8; ++w) cnt0 += wred[w];
          unsigned chosen = (krem < cnt0) ? 0u : 1u;
          if (chosen) krem -= cnt0; else val = val;    // keep val bit 0
          val |= (chosen << bit);
          #pragma unroll
          for (int k = 0; k < 4; ++k)
            cand[k] = cand[k] && (((uval[k] >> bit) & 1u) == chosen);
          __syncthreads();
        }
        if (tid == 0) { resv2[hh][j] = val; resf2[hh][j] = 1u; }
        __syncthreads();
      }
    }

    // ---------------- tau publish: one thread per half ----------------
    if (t2 == 0) {
      float s255 = __uint_as_float(resv2[half][0]);
      float s256 = __uint_as_float(resv2[half][1]);
      float s767 = __uint_as_float(resv2[half][2]);
      float s768 = __uint_as_float(resv2[half][3]);
      float tb = 0.75f * s767 + 0.25f * s768;           // quantile(score, .75)
      float tc = -(0.75f * s256 + 0.25f * s255);        // quantile(-score, .75)
      st64(&tauB64[srow], (want << 32) | (ull)__float_as_uint(tb));
      st64(&tauC64[srow], (want << 32) | (ull)__float_as_uint(tc));
    }

    // ---------------- tau gather: 256 pollers -> LDS broadcast ----------------
    if (tid < 256) {
      const ull* src = (tid < 128) ? &tauB64[tid] : &tauC64[tid - 128];
      ull v2 = ld64(src);
      while ((v2 >> 32) != want) { __builtin_amdgcn_s_sleep(1); v2 = ld64(src); }
      tauLds[tid] = __uint_as_float((unsigned)v2);
    }
    __syncthreads();                                   // B9

    // ---------------- Phase 3: gates, s-updates, events, theta/corr, reentry ----------
    float gB[4];
    float e0 = 0.f, e1 = 0.f;
    #pragma unroll
    for (int k = 0; k < 4; ++k) {
      float tb = tauLds[rg + 32 * k];
      float tc = tauLds[128 + rg + 32 * k];
      float sc = score[k];                             // own score
      gB[k] = 1.0f / (1.0f + expf(-5.0f * (sc - tb)));
      float gC = 1.0f / (1.0f + expf(-5.0f * (-sc - tc)));
      sB[k] = lf * sB[k] + proj[k] * gB[k];
      sC[k] = lf * sC[k] + proj[k] * gC;
      e0 += (sB[k] >= theta) ? 1.0f : 0.0f;            // old theta
      e1 += (sC[k] >= theta) ? 1.0f : 0.0f;
    }
    #pragma unroll
    for (int m = 16; m < 64; m <<= 1) {
      e0 += __shfl_xor(e0, m);
      e1 += __shfl_xor(e1, m);
    }
    if (lane < 16) { pev[wid][lane][0] = e0; pev[wid][lane][1] = e1; }
    __syncthreads();                                   // B10
    if (tid < 32) {   // summers
      int sfl = tid >> 1, q = tid & 1;
      float s = 0.f;
      #pragma unroll
      for (int w = 0; w < 8; ++w) s += pev[w][sfl][q];
      evfin[sfl][q] = s;
    }
    __syncthreads();                                   // B11
    float cB = evfin[fl][0];
    float cC = evfin[fl][1];
    float th1 = theta + 0.01f * (cB * 0.0078125f) - 0.01f * (cC * 0.0078125f);
    theta = fminf(fmaxf(th1 - 0.01f * (th1 - 0.1f), 0.01f), 10.0f);
    bool corr = (cB > 0.f);
    #pragma unroll
    for (int k = 0; k < 4; ++k) {
      float fac_re = corr ? (c002 + 0.1f * gB[k]) : 1.0f;
      float fac_im = corr ? s002 : 0.0f;
      X_re[k] = Xm_re[k] * fac_re - Xm_im[k] * fac_im;
      X_im[k] = Xm_re[k] * fac_im + Xm_im[k] * fac_re;
      ur[k] = ur_n[k]; ui[k] = ui_n[k];
    }
  }
}

extern "C" void kernel_launch(void* const* d_in, const int* in_sizes, int n_in,
                              void* d_out, int out_size, void* d_ws, size_t ws_size,
                              hipStream_t stream) {
  const float* in_re = (const float*)d_in[0];
  const float* in_im = (const float*)d_in[1];
  const float* r_re  = (const float*)d_in[2];
  const float* r_im  = (const float*)d_in[3];
  const float* amap  = (const float*)d_in[4];
  const float* lmap  = (const float*)d_in[5];
  float* out = (float*)d_out;
  ull* ws = (ull*)d_ws;
  // zero all tag words (scores + taus) so no stale tag can match
  hipMemsetAsync(d_ws, 0, (size_t)(BF + 256) * 8, stream);
  hipLaunchKernelGGL(ResonatorABC_82094004896068_kernel,
                     dim3(NWG), dim3(NTH), 0, stream,
                     in_re, in_im, r_re, r_im, amap, lmap, out, ws);
}

// Round 14
// 1209.734 us; speedup vs baseline: 1.1473x; 1.1473x over previous
//
#include <hip/hip_runtime.h>
#include <math.h>

// Persistent-kernel ResonatorABC scan — tagged dataflow + linear-bin exact select
// + per-consumer TAU MAILBOXES (writer-side fan-out).
// FINAL CONFIGURATION — exact R8/R12 code (best measured: 1098 & 1203 us).
// Design-space summary (all measured): tagged dataflow > barriers (R1-R3);
// linear-bin select > radix/arrival/adaptive (R4,R5,R9,R10); 4 waves/WG > 16/8
// (R5,R7,R13); sleep(1) pacing > backoff/hot (R9,R10); 64-bit tags > 32-bit
// parity (R11); 128 WGs > 64 (R13). Floor = 2 dependent cross-XCD rendezvous
// per step x 128 steps (latency-bound; HBM 7%, VALU 7.5% — no throughput wall).
// Grid: 128 WGs x 256 threads (4 waves). WG w owns features [8w,8w+8) for ALL
// 128 rows; each thread owns 4 (b,f) elements: b = rg+32k, f = 8w+fl.

#define T_STEPS 128
#define B_DIM   128
#define F_DIM   1024
#define NWG     128
#define NTH     256
#define BF      (B_DIM * F_DIM)

typedef unsigned long long ull;

__device__ __forceinline__ ull ld64(const ull* p) {
  return __hip_atomic_load(p, __ATOMIC_RELAXED, __HIP_MEMORY_SCOPE_AGENT);
}
__device__ __forceinline__ void st64(ull* p, ull v) {
  __hip_atomic_store(p, v, __ATOMIC_RELAXED, __HIP_MEMORY_SCOPE_AGENT);
}

extern "C" __global__ void __launch_bounds__(NTH)
ResonatorABC_82094004896068_kernel(
    const float* __restrict__ in_re, const float* __restrict__ in_im,
    const float* __restrict__ r_re_p, const float* __restrict__ r_im_p,
    const float* __restrict__ alpha_map, const float* __restrict__ lambda_map,
    float* __restrict__ out, ull* __restrict__ ws)
{
  const int tid  = threadIdx.x;
  const int wg   = blockIdx.x;
  const int fl   = tid & 7;         // feature-local index
  const int rg   = tid >> 3;        // row-group base (0..31); rows rg+32k
  const int f    = (wg << 3) + fl;  // global feature
  const int wid  = tid >> 6;        // wave id (0..3)
  const int lane = tid & 63;

  ull* score64 = ws;                // [B][F] {tag|score_bits}
  ull* taubox  = ws + BF;           // [128 consumers][256 slots] {tag|tau_bits}
                                    // slot b: tauB row b; slot 128+b: tauC row b

  __shared__ __align__(16) float pamp[4][8][4];   // wave partials: amp, amp2, unit_re, unit_im
  __shared__ __align__(16) float pfin[8][4];      // final per-feature sums
  __shared__ __align__(16) float pev[4][8][2];    // wave partials: evB, evC
  __shared__ __align__(16) float evfin[8][2];     // final per-feature event sums
  __shared__ __align__(16) unsigned h[1024];      // histogram (1024 bins)
  __shared__ unsigned wsum[4];                    // per-wave scan totals
  __shared__ unsigned mmw[4][2];                  // per-wave min/max
  __shared__ unsigned tbin[4], tbase[4], tcnt[4]; // located rank bins
  __shared__ unsigned lcnt[4];                    // list counters
  __shared__ unsigned lists[4][256];              // extracted bin values
  __shared__ unsigned resv[4], resf[4];           // resolved rank values/flags
  __shared__ unsigned rmm[2];                     // refine min/max
  __shared__ unsigned t2[3];                      // refine located bin/base/cnt
  __shared__ float tauLds[256];                   // gathered taus

  const float af = fminf(fmaxf(0.97f + 0.05f * tanhf(alpha_map[f]), 0.90f), 0.995f);
  const float lf = fminf(fmaxf(0.95f + 0.05f * tanhf(lambda_map[f]), 0.90f), 0.995f);
  const float rr = r_re_p[f];
  const float ri = r_im_p[f];
  const float c002 = cosf(0.02f);
  const float s002 = sinf(0.02f);

  // per-element carried state (4 rows of feature f)
  float X_re[4] = {0.f,0.f,0.f,0.f}, X_im[4] = {0.f,0.f,0.f,0.f};
  float sA[4] = {0.f,0.f,0.f,0.f}, sB[4] = {0.f,0.f,0.f,0.f}, sC[4] = {0.f,0.f,0.f,0.f};
  // per-feature carried state (single copy)
  float mu = 0.f, var = 0.01f, theta = 0.1f, ema_re = 0.f, ema_im = 0.f;

  int idx[4];
  float ur[4], ui[4];
  #pragma unroll
  for (int k = 0; k < 4; ++k) {
    idx[k] = (rg + 32 * k) * F_DIM + f;
    ur[k] = in_re[idx[k]];
    ui[k] = in_im[idx[k]];
  }

  const unsigned KR[4] = {255u, 256u, 767u, 768u};

  for (int t = 0; t < T_STEPS; ++t) {
    const ull want = (ull)(t + 1);

    *(uint4*)&h[4 * tid] = make_uint4(0u, 0u, 0u, 0u);   // zero hist (covered by phase-1 syncs)

    // ---------------- Phase 1: elementwise + B-reduced stats + score ----------------
    float Xm_re[4], Xm_im[4], proj[4], amp[4], score[4];
    float a0 = 0.f, a1 = 0.f, a2 = 0.f, a3 = 0.f;
    #pragma unroll
    for (int k = 0; k < 4; ++k) {
      Xm_re[k] = af * X_re[k] + ur[k];
      Xm_im[k] = af * X_im[k] + ui[k];
      float amp2 = Xm_re[k] * Xm_re[k] + Xm_im[k] * Xm_im[k];
      amp[k] = sqrtf(amp2);
      float invamp = (amp[k] > 0.f) ? (1.0f / amp[k]) : 0.f;
      float un_re = (amp[k] > 0.f) ? (Xm_re[k] * invamp) : 1.0f;  // angle(0)=0 -> unit=1
      float un_im = Xm_im[k] * invamp;
      proj[k] = Xm_re[k] * rr + Xm_im[k] * ri;                    // Re(X_mid*conj(r))
      sA[k] = lf * sA[k] + proj[k];
      out[t * BF + idx[k]] = sA[k];
      a0 += amp[k]; a1 += amp2; a2 += un_re; a3 += un_im;
    }
    #pragma unroll
    for (int m = 8; m < 64; m <<= 1) {   // reduce over row-groups within wave
      a0 += __shfl_xor(a0, m);
      a1 += __shfl_xor(a1, m);
      a2 += __shfl_xor(a2, m);
      a3 += __shfl_xor(a3, m);
    }
    if (lane < 8) { *(float4*)&pamp[wid][lane][0] = make_float4(a0, a1, a2, a3); }
    __syncthreads();
    if (tid < 32) {   // summers: one per (feature, quantity)
      int sfl = tid >> 2, q = tid & 3;
      pfin[sfl][q] = pamp[0][sfl][q] + pamp[1][sfl][q] + pamp[2][sfl][q] + pamp[3][sfl][q];
    }
    __syncthreads();
    float4 SS = *(const float4*)&pfin[fl][0];
    float m1 = SS.x * 0.0078125f;      // mean(amp)
    float m2 = SS.y * 0.0078125f;      // mean(amp^2)
    mu = 0.9f * mu + 0.1f * m1;
    float vm = m2 - 2.f * mu * m1 + mu * mu;
    vm = fmaxf(vm, 0.f);
    var = 0.9f * var + 0.1f * vm;
    ema_re = 0.9f * ema_re + 0.1f * (SS.z * 0.0078125f);
    ema_im = 0.9f * ema_im + 0.1f * (SS.w * 0.0078125f);
    float plv = sqrtf(ema_re * ema_re + ema_im * ema_im);
    float sden = sqrtf(var) + 1e-3f;
    #pragma unroll
    for (int k = 0; k < 4; ++k) {
      float zs = (amp[k] - mu) / sden;
      score[k] = amp[k] + 0.5f * fabsf(zs) + 0.5f * (1.0f - plv);
      st64(&score64[idx[k]], (want << 32) | (ull)__float_as_uint(score[k]));
    }

    // prefetch next-step inputs; latency hidden behind select
    float ur_n[4] = {0.f,0.f,0.f,0.f}, ui_n[4] = {0.f,0.f,0.f,0.f};
    if (t + 1 < T_STEPS) {
      #pragma unroll
      for (int k = 0; k < 4; ++k) {
        ur_n[k] = in_re[(t + 1) * BF + idx[k]];
        ui_n[k] = in_im[(t + 1) * BF + idx[k]];
      }
    }

    // ---------------- Phase 2: exact select of ranks {255,256,767,768} for row wg ----
    unsigned uval[4], bin[4];
    {
      // concurrent 4-way poll: all 4 loads in flight, re-poll only stale words
      const ull* sp0 = &score64[wg * F_DIM + tid];
      ull v[4]; bool ok[4] = {false, false, false, false};
      int remaining = 4;
      while (remaining) {
        #pragma unroll
        for (int k = 0; k < 4; ++k) if (!ok[k]) v[k] = ld64(sp0 + 256 * k);
        #pragma unroll
        for (int k = 0; k < 4; ++k) {
          if (!ok[k] && (v[k] >> 32) == want) { ok[k] = true; uval[k] = (unsigned)v[k]; --remaining; }
        }
        if (remaining) __builtin_amdgcn_s_sleep(1);
      }
    }
    unsigned umin = min(min(uval[0], uval[1]), min(uval[2], uval[3]));
    unsigned umax = max(max(uval[0], uval[1]), max(uval[2], uval[3]));
    #pragma unroll
    for (int m = 1; m < 64; m <<= 1) {
      umin = min(umin, (unsigned)__shfl_xor((int)umin, m));
      umax = max(umax, (unsigned)__shfl_xor((int)umax, m));
    }
    if (lane == 0) { mmw[wid][0] = umin; mmw[wid][1] = umax; }
    __syncthreads();
    unsigned lo = min(min(mmw[0][0], mmw[1][0]), min(mmw[2][0], mmw[3][0]));
    unsigned hi = max(max(mmw[0][1], mmw[1][1]), max(mmw[2][1], mmw[3][1]));

    if (lo != hi) {
      ull rng = (ull)hi - (ull)lo + 1ull;
      ull inv = (1ull << 40) / rng;      // floor; bin map monotone, bounded <=1023
      #pragma unroll
      for (int k = 0; k < 4; ++k) {
        bin[k] = (unsigned)((((ull)(uval[k] - lo)) * inv) >> 30);
        atomicAdd(&h[bin[k]], 1u);
      }
      if (tid < 4) { lcnt[tid] = 0u; resf[tid] = 0u; }
      __syncthreads();
      // scan: thread owns 4 consecutive bins
      uint4 hc = *(const uint4*)&h[4 * tid];
      unsigned s4 = hc.x + hc.y + hc.z + hc.w;
      unsigned incl = s4;
      #pragma unroll
      for (int d = 1; d < 64; d <<= 1) {
        unsigned vv = __shfl_up(incl, d);
        if (lane >= d) incl += vv;
      }
      if (lane == 63) wsum[wid] = incl;
      __syncthreads();
      unsigned woff = 0u;
      for (int w = 0; w < 4; ++w) if (w < wid) woff += wsum[w];
      unsigned gexcl = woff + incl - s4;       // exclusive base of my 4-bin group
      unsigned cv[4] = {hc.x, hc.y, hc.z, hc.w};
      unsigned bb[4];
      bb[0] = gexcl; bb[1] = bb[0] + cv[0]; bb[2] = bb[1] + cv[1]; bb[3] = bb[2] + cv[2];
      #pragma unroll
      for (int i = 0; i < 4; ++i) {
        if (cv[i] > 0u) {
          #pragma unroll
          for (int r = 0; r < 4; ++r) {
            if (bb[i] <= KR[r] && KR[r] < bb[i] + cv[i]) {
              tbin[r] = 4 * tid + i; tbase[r] = bb[i]; tcnt[r] = cv[i];
            }
          }
        }
      }
      __syncthreads();
      // build lists (dedup: add to first list of each distinct bin; tbin non-decreasing)
      unsigned b0 = tbin[0], b1 = tbin[1], b2 = tbin[2], b3 = tbin[3];
      #pragma unroll
      for (int k = 0; k < 4; ++k) {
        unsigned bk = bin[k], uv = uval[k];
        if (bk == b0) { unsigned s = atomicAdd(&lcnt[0], 1u); if (s < 256u) lists[0][s] = uv; }
        else if (bk == b1 && b1 != b0) { unsigned s = atomicAdd(&lcnt[1], 1u); if (s < 256u) lists[1][s] = uv; }
        else if (bk == b2 && b2 != b1) { unsigned s = atomicAdd(&lcnt[2], 1u); if (s < 256u) lists[2][s] = uv; }
        else if (bk == b3 && b3 != b2) { unsigned s = atomicAdd(&lcnt[3], 1u); if (s < 256u) lists[3][s] = uv; }
      }
      __syncthreads();
      {   // wave j resolves rank j (all 4 waves busy)
        const int j = wid;
        int src = j;
        while (src > 0 && tbin[src - 1] == tbin[j]) --src;   // uniform per wave
        unsigned c = tcnt[j];
        if (c <= 256u) {
          unsigned kk = KR[j] - tbase[j];
          for (int bi = 0; bi < (int)c; bi += 64) {
            int i = bi + lane;
            if (i < (int)c) {
              unsigned e = lists[src][i];
              unsigned r = 0;
              for (int q = 0; q < (int)c; ++q) {
                unsigned x = lists[src][q];
                r += (x < e || (x == e && q < i)) ? 1u : 0u;
              }
              if (r == kk) { resv[j] = e; resf[j] = 1u; }
            }
          }
        }
      }
      __syncthreads();
      // rare exact refine for any unresolved rank (degenerate duplicate-heavy bins)
      for (int j = 0; j < 4; ++j) {
        if (resf[j]) continue;   // uniform (LDS, post-sync)
        bool inj[4];
        #pragma unroll
        for (int k = 0; k < 4; ++k) inj[k] = (bin[k] == tbin[j]);
        unsigned krem = KR[j] - tbase[j];
        for (int iter = 0; iter < 40; ++iter) {
          if (tid == 0) { rmm[0] = 0xFFFFFFFFu; rmm[1] = 0u; }
          __syncthreads();
          #pragma unroll
          for (int k = 0; k < 4; ++k)
            if (inj[k]) { atomicMin(&rmm[0], uval[k]); atomicMax(&rmm[1], uval[k]); }
          __syncthreads();
          unsigned wlo = rmm[0], whi = rmm[1];
          if (wlo == whi) { if (tid == 0) { resv[j] = wlo; resf[j] = 1u; } __syncthreads(); break; }
          *(uint4*)&h[4 * tid] = make_uint4(0u, 0u, 0u, 0u);
          __syncthreads();
          ull rng2 = (ull)whi - (ull)wlo + 1ull;
          ull inv2 = (1ull << 40) / rng2;
          unsigned nb[4];
          #pragma unroll
          for (int k = 0; k < 4; ++k) {
            nb[k] = inj[k] ? (unsigned)((((ull)(uval[k] - wlo)) * inv2) >> 30) : 0u;
            if (inj[k]) atomicAdd(&h[nb[k]], 1u);
          }
          __syncthreads();
          uint4 hc2 = *(const uint4*)&h[4 * tid];
          unsigned s42 = hc2.x + hc2.y + hc2.z + hc2.w;
          unsigned incl2 = s42;
          #pragma unroll
          for (int d = 1; d < 64; d <<= 1) {
            unsigned vv = __shfl_up(incl2, d);
            if (lane >= d) incl2 += vv;
          }
          if (lane == 63) wsum[wid] = incl2;
          if (tid == 0) lcnt[0] = 0u;
          __syncthreads();
          unsigned woff2 = 0u;
          for (int w = 0; w < 4; ++w) if (w < wid) woff2 += wsum[w];
          unsigned gexcl2 = woff2 + incl2 - s42;
          unsigned cv2[4] = {hc2.x, hc2.y, hc2.z, hc2.w};
          unsigned bb2[4];
          bb2[0] = gexcl2; bb2[1] = bb2[0] + cv2[0]; bb2[2] = bb2[1] + cv2[1]; bb2[3] = bb2[2] + cv2[2];
          #pragma unroll
          for (int i = 0; i < 4; ++i) {
            if (cv2[i] > 0u && bb2[i] <= krem && krem < bb2[i] + cv2[i]) {
              t2[0] = 4 * tid + i; t2[1] = bb2[i]; t2[2] = cv2[i];
            }
          }
          __syncthreads();
          unsigned nbin = t2[0], nbase = t2[1], ncnt = t2[2];
          bool newin[4];
          #pragma unroll
          for (int k = 0; k < 4; ++k) newin[k] = inj[k] && (nb[k] == nbin);
          if (ncnt <= 256u) {
            #pragma unroll
            for (int k = 0; k < 4; ++k)
              if (newin[k]) { unsigned s = atomicAdd(&lcnt[0], 1u); if (s < 256u) lists[0][s] = uval[k]; }
            __syncthreads();
            if (wid == 0) {
              unsigned kk2 = krem - nbase;
              for (int bi = 0; bi < (int)ncnt; bi += 64) {
                int i = bi + lane;
                if (i < (int)ncnt) {
                  unsigned e = lists[0][i];
                  unsigned r = 0;
                  for (int q = 0; q < (int)ncnt; ++q) {
                    unsigned x = lists[0][q];
                    r += (x < e || (x == e && q < i)) ? 1u : 0u;
                  }
                  if (r == kk2) { resv[j] = e; resf[j] = 1u; }
                }
              }
            }
            __syncthreads();
            break;
          }
          #pragma unroll
          for (int k = 0; k < 4; ++k) inj[k] = newin[k];
          krem -= nbase;
        }
      }
    } else {
      if (tid < 4) { resv[tid] = lo; resf[tid] = 1u; }
      __syncthreads();
    }

    // ---------------- tau publish: fan out to all 128 consumer mailboxes ----------
    {
      // resv[] visible to all threads (post-sync). All threads compute both taus.
      float s255 = __uint_as_float(resv[0]);
      float s256 = __uint_as_float(resv[1]);
      float s767 = __uint_as_float(resv[2]);
      float s768 = __uint_as_float(resv[3]);
      float tb = 0.75f * s767 + 0.25f * s768;           // quantile(score, .75)
      float tc = -(0.75f * s256 + 0.25f * s255);        // quantile(-score, .75)
      int c = tid & 127;                                // consumer WG
      ull w = (tid < 128)
            ? ((want << 32) | (ull)__float_as_uint(tb))
            : ((want << 32) | (ull)__float_as_uint(tc));
      int slot = (tid < 128) ? wg : (128 + wg);
      st64(&taubox[(ull)c * 256 + slot], w);
    }

    // ---------------- tau gather: poll OWN mailbox (sole reader) -> LDS ----------
    {
      const ull* src = &taubox[(ull)wg * 256 + tid];
      ull v2 = ld64(src);
      while ((v2 >> 32) != want) { __builtin_amdgcn_s_sleep(1); v2 = ld64(src); }
      tauLds[tid] = __uint_as_float((unsigned)v2);
    }
    __syncthreads();

    // ---------------- Phase 3: gates, s-updates, events, theta/corr, reentry ----------
    float gB[4];
    float e0 = 0.f, e1 = 0.f;
    #pragma unroll
    for (int k = 0; k < 4; ++k) {
      float tb = tauLds[rg + 32 * k];
      float tc = tauLds[128 + rg + 32 * k];
      float sc = score[k];                   // own score
      gB[k] = 1.0f / (1.0f + expf(-5.0f * (sc - tb)));
      float gC = 1.0f / (1.0f + expf(-5.0f * (-sc - tc)));
      sB[k] = lf * sB[k] + proj[k] * gB[k];
      sC[k] = lf * sC[k] + proj[k] * gC;
      e0 += (sB[k] >= theta) ? 1.0f : 0.0f;   // old theta
      e1 += (sC[k] >= theta) ? 1.0f : 0.0f;
    }
    #pragma unroll
    for (int m = 8; m < 64; m <<= 1) {
      e0 += __shfl_xor(e0, m);
      e1 += __shfl_xor(e1, m);
    }
    if (lane < 8) { pev[wid][lane][0] = e0; pev[wid][lane][1] = e1; }
    __syncthreads();
    if (tid < 16) {   // summers
      int sfl = tid >> 1, q = tid & 1;
      evfin[sfl][q] = pev[0][sfl][q] + pev[1][sfl][q] + pev[2][sfl][q] + pev[3][sfl][q];
    }
    __syncthreads();
    float cB = evfin[fl][0];
    float cC = evfin[fl][1];
    float th1 = theta + 0.01f * (cB * 0.0078125f) - 0.01f * (cC * 0.0078125f);
    theta = fminf(fmaxf(th1 - 0.01f * (th1 - 0.1f), 0.01f), 10.0f);
    bool corr = (cB > 0.f);
    #pragma unroll
    for (int k = 0; k < 4; ++k) {
      float fac_re = corr ? (c002 + 0.1f * gB[k]) : 1.0f;
      float fac_im = corr ? s002 : 0.0f;
      X_re[k] = Xm_re[k] * fac_re - Xm_im[k] * fac_im;
      X_im[k] = Xm_re[k] * fac_im + Xm_im[k] * fac_re;
      ur[k] = ur_n[k]; ui[k] = ui_n[k];
    }
  }
}

extern "C" void kernel_launch(void* const* d_in, const int* in_sizes, int n_in,
                              void* d_out, int out_size, void* d_ws, size_t ws_size,
                              hipStream_t stream) {
  const float* in_re = (const float*)d_in[0];
  const float* in_im = (const float*)d_in[1];
  const float* r_re  = (const float*)d_in[2];
  const float* r_im  = (const float*)d_in[3];
  const float* amap  = (const float*)d_in[4];
  const float* lmap  = (const float*)d_in[5];
  float* out = (float*)d_out;
  ull* ws = (ull*)d_ws;
  // zero all tag words (score + mailboxes) so no stale tag can match
  hipMemsetAsync(d_ws, 0, (size_t)(BF + 128 * 256) * 8, stream);
  hipLaunchKernelGGL(ResonatorABC_82094004896068_kernel,
                     dim3(NWG), dim3(NTH), 0, stream,
                     in_re, in_im, r_re, r_im, amap, lmap, out, ws);
}